// Round 1
// baseline (2055.909 us; speedup 1.0000x reference)
//
#include <hip/hip_runtime.h>
#include <math.h>

typedef __attribute__((ext_vector_type(8))) short short8;
typedef __attribute__((ext_vector_type(4))) float f32x4;

#define BM 128
#define BN 128
#define BK 32

#define EPI_BF16   0
#define EPI_SCORES 1
#define EPI_R      2
#define EPI_Z      3
#define EPI_N      4

__device__ __forceinline__ unsigned short f2bf(float f) {
    unsigned int u = __float_as_uint(f);
    u += 0x7fffu + ((u >> 16) & 1u);
    return (unsigned short)(u >> 16);
}
__device__ __forceinline__ float bf2f(unsigned short s) {
    return __uint_as_float(((unsigned int)s) << 16);
}

struct alignas(8) us4 { unsigned short a, b, c, d; };

#define GLD_LDS16(gp, lp) \
    __builtin_amdgcn_global_load_lds((const __attribute__((address_space(1))) unsigned int*)(gp), \
                                     (__attribute__((address_space(3))) unsigned int*)(lp), 16, 0, 0)

// C = A(M,K) @ Bt(N,K)^T, bf16 inputs, fp32 accumulate, fused epilogues.
template<int EPI>
__global__ void __launch_bounds__(256)
gemm_bt(const unsigned short* __restrict__ A, long long sAb, int lda,
        const unsigned short* __restrict__ Bt, long long sBb, int ldb,
        const float* __restrict__ bias,
        void* __restrict__ C, long long sCb, int ldc,
        int K, float scale,
        const float* __restrict__ hptr,
        const unsigned short* __restrict__ updptr)
{
    __shared__ unsigned short As[BM * BK];
    __shared__ unsigned short Bs[BN * BK];

    const int z = blockIdx.z;
    A  += (size_t)z * (size_t)sAb;
    Bt += (size_t)z * (size_t)sBb;

    const int m0 = blockIdx.y * BM;
    const int n0 = blockIdx.x * BN;

    const int tid = threadIdx.x;
    const int w  = tid >> 6;
    const int l  = tid & 63;
    const int lr = l & 15;
    const int lg = l >> 4;
    const int wr = w >> 1;
    const int wc = w & 1;
    const int srow = l >> 2;        // 0..15
    const int scol = (l & 3) * 8;   // 0,8,16,24

    f32x4 acc[4][4] = {};

    for (int kt = 0; kt < K; kt += BK) {
        #pragma unroll
        for (int i = 0; i < 2; ++i) {
            const int row = i * 64 + w * 16 + srow;
            GLD_LDS16(A + (size_t)(m0 + row) * lda + kt + scol, As + (i * 64 + w * 16) * BK);
        }
        #pragma unroll
        for (int i = 0; i < 2; ++i) {
            const int row = i * 64 + w * 16 + srow;
            GLD_LDS16(Bt + (size_t)(n0 + row) * ldb + kt + scol, Bs + (i * 64 + w * 16) * BK);
        }
        __syncthreads();

        short8 af[4], bfv[4];
        #pragma unroll
        for (int m = 0; m < 4; ++m)
            af[m] = *(const short8*)(As + (wr * 64 + m * 16 + lr) * BK + lg * 8);
        #pragma unroll
        for (int n = 0; n < 4; ++n)
            bfv[n] = *(const short8*)(Bs + (wc * 64 + n * 16 + lr) * BK + lg * 8);
        #pragma unroll
        for (int m = 0; m < 4; ++m)
            #pragma unroll
            for (int n = 0; n < 4; ++n)
                acc[m][n] = __builtin_amdgcn_mfma_f32_16x16x32_bf16(af[m], bfv[n], acc[m][n], 0, 0, 0);
        __syncthreads();
    }

    const int Mb = gridDim.y * BM;          // rows per batch slab
    const size_t zc = (size_t)z * (size_t)sCb;
    #pragma unroll
    for (int m = 0; m < 4; ++m) {
        #pragma unroll
        for (int n = 0; n < 4; ++n) {
            const int col = n0 + wc * 64 + n * 16 + lr;
            const float bval = bias ? bias[col] : 0.0f;
            #pragma unroll
            for (int r = 0; r < 4; ++r) {
                const int row = m0 + wr * 64 + m * 16 + lg * 4 + r;
                float v = acc[m][n][r] + bval;
                if (EPI == EPI_BF16) {
                    ((unsigned short*)C)[zc + (size_t)row * ldc + col] = f2bf(v);
                } else if (EPI == EPI_SCORES) {
                    ((float*)C)[zc + (size_t)row * ldc + col] = v * scale;
                } else if (EPI == EPI_R) {
                    const size_t flat = (size_t)z * Mb + row;
                    const float hh = hptr[flat * 1024 + col];
                    const float sg = 1.0f / (1.0f + __expf(-v));
                    ((unsigned short*)C)[flat * 2048 + 1024 + col] = f2bf(hh * sg);
                } else if (EPI == EPI_Z) {
                    const size_t flat = (size_t)z * Mb + row;
                    const float sg = 1.0f / (1.0f + __expf(-v));
                    ((unsigned short*)C)[flat * 1024 + col] = f2bf(sg);
                } else { // EPI_N
                    const size_t flat = (size_t)z * Mb + row;
                    const float u  = bf2f(updptr[flat * 1024 + col]);
                    const float hh = hptr[flat * 1024 + col];
                    ((float*)C)[flat * 1024 + col] = (1.0f - u) * hh + u * tanhf(v);
                }
            }
        }
    }
}

// xh = concat(bf16(x), bf16(h)) rows of 2048
__global__ void __launch_bounds__(256)
prep_xh(const float* __restrict__ x, const float* __restrict__ h, unsigned short* __restrict__ xh)
{
    const size_t t = (size_t)blockIdx.x * 256 + threadIdx.x;
    const size_t f = t * 4;                       // < 64*512*1024 exactly
    const size_t row = f >> 10, col = f & 1023;
    const float4 vx = *(const float4*)(x + f);
    const float4 vh = *(const float4*)(h + f);
    us4 ox = { f2bf(vx.x), f2bf(vx.y), f2bf(vx.z), f2bf(vx.w) };
    us4 oh = { f2bf(vh.x), f2bf(vh.y), f2bf(vh.z), f2bf(vh.w) };
    *(us4*)(xh + row * 2048 + col)        = ox;
    *(us4*)(xh + row * 2048 + 1024 + col) = oh;
}

// W (K=2048, N) fp32 row-major -> WT (N, 2048) bf16 row-major
__global__ void __launch_bounds__(256)
transpose_w(const float* __restrict__ W, unsigned short* __restrict__ WT, int N)
{
    __shared__ float t[32][33];
    const int k0 = blockIdx.y * 32, n0 = blockIdx.x * 32;
    const int tx = threadIdx.x & 31, ty = threadIdx.x >> 5;
    #pragma unroll
    for (int i = 0; i < 4; ++i)
        t[ty + i * 8][tx] = W[(size_t)(k0 + ty + i * 8) * N + n0 + tx];
    __syncthreads();
    #pragma unroll
    for (int i = 0; i < 4; ++i)
        WT[(size_t)(n0 + ty + i * 8) * 2048 + k0 + tx] = f2bf(t[tx][ty + i * 8]);
}

// batched (64) transpose of V (512 x 1024, row stride 2048) -> Vt (1024 x 512)
__global__ void __launch_bounds__(256)
transpose_v(const unsigned short* __restrict__ V, unsigned short* __restrict__ Vt)
{
    __shared__ unsigned short t[32][34];
    const int z = blockIdx.z;
    const unsigned short* in = V + (size_t)z * 512 * 2048;
    unsigned short* outp = Vt + (size_t)z * 1024 * 512;
    const int c0 = blockIdx.x * 32, r0 = blockIdx.y * 32;
    const int tx = threadIdx.x & 31, ty = threadIdx.x >> 5;
    #pragma unroll
    for (int i = 0; i < 4; ++i)
        t[ty + i * 8][tx] = in[(size_t)(r0 + ty + i * 8) * 2048 + c0 + tx];
    __syncthreads();
    #pragma unroll
    for (int i = 0; i < 4; ++i)
        outp[(size_t)(c0 + ty + i * 8) * 512 + r0 + tx] = t[tx][ty + i * 8];
}

// row softmax over 512 fp32 -> bf16 probs; 1 wave per row, 4 rows/block
__global__ void __launch_bounds__(256)
softmax512(const float* __restrict__ S, unsigned short* __restrict__ P)
{
    const int row = blockIdx.x * 4 + (threadIdx.x >> 6);
    const int l = threadIdx.x & 63;
    const float* s = S + (size_t)row * 512;
    const float4 v0 = ((const float4*)s)[l];
    const float4 v1 = ((const float4*)s)[64 + l];
    float m = fmaxf(fmaxf(fmaxf(v0.x, v0.y), fmaxf(v0.z, v0.w)),
                    fmaxf(fmaxf(v1.x, v1.y), fmaxf(v1.z, v1.w)));
    #pragma unroll
    for (int d = 32; d; d >>= 1) m = fmaxf(m, __shfl_xor(m, d));
    float e0 = __expf(v0.x - m), e1 = __expf(v0.y - m), e2 = __expf(v0.z - m), e3 = __expf(v0.w - m);
    float e4 = __expf(v1.x - m), e5 = __expf(v1.y - m), e6 = __expf(v1.z - m), e7 = __expf(v1.w - m);
    float sum = e0 + e1 + e2 + e3 + e4 + e5 + e6 + e7;
    #pragma unroll
    for (int d = 32; d; d >>= 1) sum += __shfl_xor(sum, d);
    const float inv = 1.0f / sum;
    unsigned short* p = P + (size_t)row * 512;
    us4 a = { f2bf(e0 * inv), f2bf(e1 * inv), f2bf(e2 * inv), f2bf(e3 * inv) };
    us4 b = { f2bf(e4 * inv), f2bf(e5 * inv), f2bf(e6 * inv), f2bf(e7 * inv) };
    ((us4*)p)[l] = a;
    ((us4*)p)[64 + l] = b;
}

// in-place LayerNorm over rows of 1024; 1 wave per row
__global__ void __launch_bounds__(256)
layernorm1024(float* __restrict__ Y, const float* __restrict__ gamma, const float* __restrict__ beta)
{
    const int row = blockIdx.x * 4 + (threadIdx.x >> 6);
    const int l = threadIdx.x & 63;
    float* p = Y + (size_t)row * 1024;
    float4 v[4];
    float s = 0.0f, s2 = 0.0f;
    #pragma unroll
    for (int i = 0; i < 4; ++i) {
        v[i] = ((const float4*)p)[i * 64 + l];
        s  += v[i].x + v[i].y + v[i].z + v[i].w;
        s2 += v[i].x * v[i].x + v[i].y * v[i].y + v[i].z * v[i].z + v[i].w * v[i].w;
    }
    #pragma unroll
    for (int d = 32; d; d >>= 1) { s += __shfl_xor(s, d); s2 += __shfl_xor(s2, d); }
    const float mu = s * (1.0f / 1024.0f);
    const float var = s2 * (1.0f / 1024.0f) - mu * mu;
    const float inv = rsqrtf(var + 1e-5f);
    #pragma unroll
    for (int i = 0; i < 4; ++i) {
        const float4 gv = ((const float4*)gamma)[i * 64 + l];
        const float4 bv = ((const float4*)beta)[i * 64 + l];
        float4 o;
        o.x = (v[i].x - mu) * inv * gv.x + bv.x;
        o.y = (v[i].y - mu) * inv * gv.y + bv.y;
        o.z = (v[i].z - mu) * inv * gv.z + bv.z;
        o.w = (v[i].w - mu) * inv * gv.w + bv.w;
        ((float4*)p)[i * 64 + l] = o;
    }
}

__global__ void __launch_bounds__(256)
concat_bias(const float* __restrict__ a, const float* __restrict__ b,
            const float* __restrict__ c, float* __restrict__ o)
{
    const int i = blockIdx.x * 256 + threadIdx.x;   // 2048 threads
    o[i] = (i < 512) ? a[i] : (i < 1024) ? b[i - 512] : c[i - 1024];
}

extern "C" void kernel_launch(void* const* d_in, const int* in_sizes, int n_in,
                              void* d_out, int out_size, void* d_ws, size_t ws_size,
                              hipStream_t stream)
{
    (void)in_sizes; (void)n_in; (void)out_size; (void)ws_size;

    const float* x = (const float*)d_in[0];
    const float* h = (const float*)d_in[1];
    const float* Wf[9]; const float* bia[9];
    for (int g = 0; g < 3; ++g)
        for (int j = 0; j < 3; ++j) {
            Wf[g * 3 + j]  = (const float*)d_in[2 + g * 6 + j * 2];
            bia[g * 3 + j] = (const float*)d_in[2 + g * 6 + j * 2 + 1];
        }
    const float* gamma = (const float*)d_in[20];
    const float* beta  = (const float*)d_in[21];
    float* out = (float*)d_out;

    char* ws = (char*)d_ws;
    size_t off = 0;
    auto alloc = [&](size_t bytes) -> void* {
        void* p = ws + off; off += (bytes + 255) & ~(size_t)255; return p;
    };
    unsigned short* xh  = (unsigned short*)alloc((size_t)32768 * 2048 * 2); // 134 MB
    unsigned short* WT  = (unsigned short*)alloc((size_t)12582912 * 2);     // 24 MB (r,z,n x qT,kT,vT)
    unsigned short* QKV = (unsigned short*)alloc((size_t)32768 * 2048 * 2); // 134 MB
    unsigned short* Vt  = (unsigned short*)alloc((size_t)32768 * 1024 * 2); // 67 MB
    float*          Sc  = (float*)alloc((size_t)64 * 512 * 512 * 4);        // 67 MB
    unsigned short* Pb  = (unsigned short*)alloc((size_t)64 * 512 * 512 * 2);// 33.5 MB
    unsigned short* upd = (unsigned short*)alloc((size_t)32768 * 1024 * 2); // 67 MB
    float*          bct = (float*)alloc((size_t)3 * 2048 * 4);

    size_t wtoff[9];
    {
        size_t o = 0;
        for (int g = 0; g < 3; ++g) {
            wtoff[g * 3 + 0] = o; o += (size_t)512 * 2048;
            wtoff[g * 3 + 1] = o; o += (size_t)512 * 2048;
            wtoff[g * 3 + 2] = o; o += (size_t)1024 * 2048;
        }
    }

    prep_xh<<<32768, 256, 0, stream>>>(x, h, xh);
    for (int i = 0; i < 9; ++i) {
        const int N = (i % 3 == 2) ? 1024 : 512;
        transpose_w<<<dim3(N / 32, 64, 1), 256, 0, stream>>>(Wf[i], WT + wtoff[i], N);
    }
    for (int g = 0; g < 3; ++g)
        concat_bias<<<8, 256, 0, stream>>>(bia[g * 3 + 0], bia[g * 3 + 1], bia[g * 3 + 2], bct + g * 2048);

    const float scscale = 0.044194173824159216f; // 1/sqrt(512)

    auto gate = [&](int g, int epi) {
        const unsigned short* wT = WT + wtoff[g * 3 + 0];  // q,k,v rows contiguous -> N=2048
        // fused QKV projection: (32768 x 2048) @ (2048 x 2048)^T
        gemm_bt<EPI_BF16><<<dim3(16, 256, 1), 256, 0, stream>>>(
            xh, 0, 2048, wT, 0, 2048, bct + g * 2048, QKV, 0, 2048, 2048, 0.0f, nullptr, nullptr);
        transpose_v<<<dim3(32, 16, 64), 256, 0, stream>>>(QKV + 1024, Vt);
        // scores = Q @ K^T * scale   (batched over 64)
        gemm_bt<EPI_SCORES><<<dim3(4, 4, 64), 256, 0, stream>>>(
            QKV, 1048576, 2048, QKV + 512, 1048576, 2048, nullptr,
            Sc, 262144, 512, 512, scscale, nullptr, nullptr);
        softmax512<<<8192, 256, 0, stream>>>(Sc, Pb);
        // PV (batched), fused gate epilogue
        if (epi == EPI_Z)
            gemm_bt<EPI_Z><<<dim3(8, 4, 64), 256, 0, stream>>>(
                Pb, 262144, 512, Vt, 524288, 512, nullptr, upd, 0, 1024, 512, 0.0f, nullptr, nullptr);
        else if (epi == EPI_R)
            gemm_bt<EPI_R><<<dim3(8, 4, 64), 256, 0, stream>>>(
                Pb, 262144, 512, Vt, 524288, 512, nullptr, xh, 0, 2048, 512, 0.0f, h, nullptr);
        else
            gemm_bt<EPI_N><<<dim3(8, 4, 64), 256, 0, stream>>>(
                Pb, 262144, 512, Vt, 524288, 512, nullptr, out, 0, 1024, 512, 0.0f, h, upd);
    };

    gate(1, EPI_Z);  // update = sigmoid(z-attn)           (reads original xh)
    gate(0, EPI_R);  // xh[:,1024:] = bf16(h * sigmoid(r)) (in-place -> xhr)
    gate(2, EPI_N);  // out = (1-u)*h + u*tanh(n-attn)
    layernorm1024<<<8192, 256, 0, stream>>>(out, gamma, beta);
}

// Round 2
// 1585.984 us; speedup vs baseline: 1.2963x; 1.2963x over previous
//
#include <hip/hip_runtime.h>
#include <math.h>

typedef __attribute__((ext_vector_type(8))) short short8;
typedef __attribute__((ext_vector_type(4))) float f32x4;

#define EPI_BF16   0
#define EPI_SCORES 1
#define EPI_R      2
#define EPI_Z      3
#define EPI_N      4

__device__ __forceinline__ unsigned short f2bf(float f) {
    unsigned int u = __float_as_uint(f);
    u += 0x7fffu + ((u >> 16) & 1u);
    return (unsigned short)(u >> 16);
}
__device__ __forceinline__ float bf2f(unsigned short s) {
    return __uint_as_float(((unsigned int)s) << 16);
}

struct alignas(8) us4 { unsigned short a, b, c, d; };

#define GLD_LDS16(gp, lp) \
    __builtin_amdgcn_global_load_lds((const __attribute__((address_space(1))) unsigned int*)(gp), \
                                     (__attribute__((address_space(3))) unsigned int*)(lp), 16, 0, 0)

__device__ __forceinline__ void BARF() {
    asm volatile("" ::: "memory");
    __builtin_amdgcn_s_barrier();
    asm volatile("" ::: "memory");
}
#define LGKM0 asm volatile("s_waitcnt lgkmcnt(0)" ::: "memory")

// ============================================================================
// 256x256 tile, BK=64, 512 threads (8 waves: 2M x 4N), 8-phase-style pipeline.
// LDS: 2 x (A 256x64 + B 256x64) bf16 = 128 KiB, XOR-swizzled (byte ^= (row&7)<<4)
// via inverse-swizzled GLOBAL source (global_load_lds writes linearly).
// Per K-tile: ph0 {read A-lo + B-lo, MFMA q00}, ph1 {read B-hi, MFMA q01},
// ph2 {read A-hi, MFMA q11}, ph3 {stage tile t+2, vmcnt(8), MFMA q10}.
// Buffer p is fully register-resident after ph2's end barrier -> safe to
// overwrite with tile t+2 in ph3. Counted vmcnt keeps 8-16 loads in flight.
// ============================================================================
template<int EPI>
__global__ void __launch_bounds__(512, 2)
gemm256(const unsigned short* __restrict__ A, long long sAb, int lda,
        const unsigned short* __restrict__ Bt, long long sBb, int ldb,
        const float* __restrict__ bias,
        void* __restrict__ C, long long sCb, int ldc,
        int K, float scale,
        const float* __restrict__ hptr,
        const unsigned short* __restrict__ updptr)
{
    extern __shared__ char smem[];   // 131072 B

    const int z = blockIdx.z;
    A  += (size_t)z * (size_t)sAb;
    Bt += (size_t)z * (size_t)sBb;
    const int m0 = blockIdx.y * 256;
    const int n0 = blockIdx.x * 256;

    const int tid = threadIdx.x;
    const int w  = tid >> 6;      // wave 0..7
    const int l  = tid & 63;
    const int wr = w >> 2;        // 0..1 (M half: 128 rows)
    const int wc = w & 3;         // 0..3 (N quarter: 64 cols)
    const int lr = l & 15;
    const int lg = l >> 4;
    const int rs = (lr & 7) << 4; // read-side XOR swizzle

    // staging decomposition: lane l covers row (w*8 + l>>3), 16B col (l&7)*16
    const int srw = l >> 3;
    const int scb = ((l & 7) << 4) ^ (srw << 4);  // inverse-swizzled source col byte
    const int ldsw = w << 10;                      // wave's 1 KiB chunk

    const long long ldab = (long long)lda * 2;
    const long long ldbb = (long long)ldb * 2;

    f32x4 acc[2][4][4] = {};
    short8 a[4][2], b[4][2];

#define STAGE_A(kt, buf) { \
    const char* g_ = (const char*)A + (size_t)(m0 + w*8 + srw) * ldab + (size_t)(kt)*2 + scb; \
    char* d_ = smem + (buf)*65536 + ldsw; \
    _Pragma("unroll") \
    for (int j = 0; j < 4; ++j) \
        GLD_LDS16(g_ + (size_t)(j*64) * ldab, d_ + j*8192); }

#define STAGE_B(kt, buf) { \
    const char* g_ = (const char*)Bt + (size_t)(n0 + w*8 + srw) * ldbb + (size_t)(kt)*2 + scb; \
    char* d_ = smem + (buf)*65536 + 32768 + ldsw; \
    _Pragma("unroll") \
    for (int j = 0; j < 4; ++j) \
        GLD_LDS16(g_ + (size_t)(j*64) * ldbb, d_ + j*8192); }

#define LDA8(MH, buf) { \
    const char* Ab_ = smem + (buf)*65536; \
    _Pragma("unroll") \
    for (int mf = 0; mf < 4; ++mf) { \
        const int row_ = wr*128 + (MH)*64 + mf*16 + lr; \
        _Pragma("unroll") \
        for (int kk = 0; kk < 2; ++kk) \
            a[mf][kk] = *(const short8*)(Ab_ + row_*128 + ((kk*64 + lg*16) ^ rs)); } }

#define LDB4(BH, buf) { \
    const char* Bb_ = smem + (buf)*65536 + 32768; \
    _Pragma("unroll") \
    for (int nf = 0; nf < 2; ++nf) { \
        const int row_ = wc*64 + (BH)*32 + nf*16 + lr; \
        _Pragma("unroll") \
        for (int kk = 0; kk < 2; ++kk) \
            b[(BH)*2+nf][kk] = *(const short8*)(Bb_ + row_*128 + ((kk*64 + lg*16) ^ rs)); } }

#define MMA16(MH, BH) { \
    __builtin_amdgcn_s_setprio(1); \
    _Pragma("unroll") \
    for (int mf = 0; mf < 4; ++mf) \
    _Pragma("unroll") \
    for (int nf = 0; nf < 2; ++nf) \
    _Pragma("unroll") \
    for (int kk = 0; kk < 2; ++kk) \
        acc[MH][mf][(BH)*2+nf] = __builtin_amdgcn_mfma_f32_16x16x32_bf16( \
            a[mf][kk], b[(BH)*2+nf][kk], acc[MH][mf][(BH)*2+nf], 0, 0, 0); \
    __builtin_amdgcn_s_setprio(0); }

    // prologue: tile 0 -> buf0, tile 1 -> buf1
    STAGE_A(0, 0); STAGE_B(0, 0);
    STAGE_A(64, 1); STAGE_B(64, 1);
    asm volatile("s_waitcnt vmcnt(8)" ::: "memory");   // tile 0 landed
    BARF();

    const int NT = K >> 6;
    for (int t = 0; t < NT; ++t) {
        const int p = t & 1;
        // phase 0: A-lo(8 reads) + B-lo(4 reads); MFMA (mh0 x bh0)
        LDA8(0, p); LDB4(0, p);
        BARF(); LGKM0;
        MMA16(0, 0);
        BARF();
        // phase 1: B-hi(4); MFMA (mh0 x bh1)
        LDB4(1, p);
        BARF(); LGKM0;
        MMA16(0, 1);
        BARF();
        // phase 2: A-hi(8); MFMA (mh1 x bh1)  -> buf p fully consumed after this
        LDA8(1, p);
        BARF(); LGKM0;
        MMA16(1, 1);
        BARF();
        // phase 3: stage tile t+2 into buf p; counted vmcnt guarantees tile t+1
        if (t + 2 < NT) {
            STAGE_A((t + 2) * 64, p); STAGE_B((t + 2) * 64, p);
            asm volatile("s_waitcnt vmcnt(8)" ::: "memory");
        } else {
            asm volatile("s_waitcnt vmcnt(0)" ::: "memory");
        }
        BARF();
        MMA16(1, 0);                 // regs only (a=mh1, b=bh0)
        BARF();
    }

    // epilogue
    const int Mb = gridDim.y << 8;
    const size_t zc = (size_t)z * (size_t)sCb;
    #pragma unroll
    for (int mh = 0; mh < 2; ++mh) {
        #pragma unroll
        for (int mf = 0; mf < 4; ++mf) {
            #pragma unroll
            for (int nf = 0; nf < 4; ++nf) {
                const int col = n0 + wc * 64 + nf * 16 + lr;
                const float bval = (EPI == EPI_BF16) ? bias[col] : 0.0f;
                #pragma unroll
                for (int r = 0; r < 4; ++r) {
                    const int row = m0 + wr * 128 + mh * 64 + mf * 16 + lg * 4 + r;
                    float v = acc[mh][mf][nf][r] + bval;
                    if (EPI == EPI_BF16) {
                        ((unsigned short*)C)[zc + (size_t)row * ldc + col] = f2bf(v);
                    } else if (EPI == EPI_SCORES) {
                        ((float*)C)[zc + (size_t)row * ldc + col] = v * scale;
                    } else if (EPI == EPI_R) {
                        const size_t flat = (size_t)z * Mb + row;
                        const float hh = hptr[flat * 1024 + col];
                        const float sg = 1.0f / (1.0f + __expf(-v));
                        ((unsigned short*)C)[flat * 2048 + 1024 + col] = f2bf(hh * sg);
                    } else if (EPI == EPI_Z) {
                        const size_t flat = (size_t)z * Mb + row;
                        const float sg = 1.0f / (1.0f + __expf(-v));
                        ((unsigned short*)C)[flat * 1024 + col] = f2bf(sg);
                    } else { // EPI_N
                        const size_t flat = (size_t)z * Mb + row;
                        const float u  = bf2f(updptr[flat * 1024 + col]);
                        const float hh = hptr[flat * 1024 + col];
                        ((float*)C)[flat * 1024 + col] = (1.0f - u) * hh + u * tanhf(v);
                    }
                }
            }
        }
    }
#undef STAGE_A
#undef STAGE_B
#undef LDA8
#undef LDB4
#undef MMA16
}

// ============================================================================
// memory-bound helper kernels (unchanged from round 1)
// ============================================================================

__global__ void __launch_bounds__(256)
prep_xh(const float* __restrict__ x, const float* __restrict__ h, unsigned short* __restrict__ xh)
{
    const size_t t = (size_t)blockIdx.x * 256 + threadIdx.x;
    const size_t f = t * 4;
    const size_t row = f >> 10, col = f & 1023;
    const float4 vx = *(const float4*)(x + f);
    const float4 vh = *(const float4*)(h + f);
    us4 ox = { f2bf(vx.x), f2bf(vx.y), f2bf(vx.z), f2bf(vx.w) };
    us4 oh = { f2bf(vh.x), f2bf(vh.y), f2bf(vh.z), f2bf(vh.w) };
    *(us4*)(xh + row * 2048 + col)        = ox;
    *(us4*)(xh + row * 2048 + 1024 + col) = oh;
}

__global__ void __launch_bounds__(256)
transpose_w(const float* __restrict__ W, unsigned short* __restrict__ WT, int N)
{
    __shared__ float t[32][33];
    const int k0 = blockIdx.y * 32, n0 = blockIdx.x * 32;
    const int tx = threadIdx.x & 31, ty = threadIdx.x >> 5;
    #pragma unroll
    for (int i = 0; i < 4; ++i)
        t[ty + i * 8][tx] = W[(size_t)(k0 + ty + i * 8) * N + n0 + tx];
    __syncthreads();
    #pragma unroll
    for (int i = 0; i < 4; ++i)
        WT[(size_t)(n0 + ty + i * 8) * 2048 + k0 + tx] = f2bf(t[tx][ty + i * 8]);
}

__global__ void __launch_bounds__(256)
transpose_v(const unsigned short* __restrict__ V, unsigned short* __restrict__ Vt)
{
    __shared__ unsigned short t[32][34];
    const int z = blockIdx.z;
    const unsigned short* in = V + (size_t)z * 512 * 2048;
    unsigned short* outp = Vt + (size_t)z * 1024 * 512;
    const int c0 = blockIdx.x * 32, r0 = blockIdx.y * 32;
    const int tx = threadIdx.x & 31, ty = threadIdx.x >> 5;
    #pragma unroll
    for (int i = 0; i < 4; ++i)
        t[ty + i * 8][tx] = in[(size_t)(r0 + ty + i * 8) * 2048 + c0 + tx];
    __syncthreads();
    #pragma unroll
    for (int i = 0; i < 4; ++i)
        outp[(size_t)(c0 + ty + i * 8) * 512 + r0 + tx] = t[tx][ty + i * 8];
}

__global__ void __launch_bounds__(256)
softmax512(const float* __restrict__ S, unsigned short* __restrict__ P)
{
    const int row = blockIdx.x * 4 + (threadIdx.x >> 6);
    const int l = threadIdx.x & 63;
    const float* s = S + (size_t)row * 512;
    const float4 v0 = ((const float4*)s)[l];
    const float4 v1 = ((const float4*)s)[64 + l];
    float m = fmaxf(fmaxf(fmaxf(v0.x, v0.y), fmaxf(v0.z, v0.w)),
                    fmaxf(fmaxf(v1.x, v1.y), fmaxf(v1.z, v1.w)));
    #pragma unroll
    for (int d = 32; d; d >>= 1) m = fmaxf(m, __shfl_xor(m, d));
    float e0 = __expf(v0.x - m), e1 = __expf(v0.y - m), e2 = __expf(v0.z - m), e3 = __expf(v0.w - m);
    float e4 = __expf(v1.x - m), e5 = __expf(v1.y - m), e6 = __expf(v1.z - m), e7 = __expf(v1.w - m);
    float sum = e0 + e1 + e2 + e3 + e4 + e5 + e6 + e7;
    #pragma unroll
    for (int d = 32; d; d >>= 1) sum += __shfl_xor(sum, d);
    const float inv = 1.0f / sum;
    unsigned short* p = P + (size_t)row * 512;
    us4 aa = { f2bf(e0 * inv), f2bf(e1 * inv), f2bf(e2 * inv), f2bf(e3 * inv) };
    us4 bb = { f2bf(e4 * inv), f2bf(e5 * inv), f2bf(e6 * inv), f2bf(e7 * inv) };
    ((us4*)p)[l] = aa;
    ((us4*)p)[64 + l] = bb;
}

__global__ void __launch_bounds__(256)
layernorm1024(float* __restrict__ Y, const float* __restrict__ gamma, const float* __restrict__ beta)
{
    const int row = blockIdx.x * 4 + (threadIdx.x >> 6);
    const int l = threadIdx.x & 63;
    float* p = Y + (size_t)row * 1024;
    float4 v[4];
    float s = 0.0f, s2 = 0.0f;
    #pragma unroll
    for (int i = 0; i < 4; ++i) {
        v[i] = ((const float4*)p)[i * 64 + l];
        s  += v[i].x + v[i].y + v[i].z + v[i].w;
        s2 += v[i].x * v[i].x + v[i].y * v[i].y + v[i].z * v[i].z + v[i].w * v[i].w;
    }
    #pragma unroll
    for (int d = 32; d; d >>= 1) { s += __shfl_xor(s, d); s2 += __shfl_xor(s2, d); }
    const float mu = s * (1.0f / 1024.0f);
    const float var = s2 * (1.0f / 1024.0f) - mu * mu;
    const float inv = rsqrtf(var + 1e-5f);
    #pragma unroll
    for (int i = 0; i < 4; ++i) {
        const float4 gv = ((const float4*)gamma)[i * 64 + l];
        const float4 bv = ((const float4*)beta)[i * 64 + l];
        float4 o;
        o.x = (v[i].x - mu) * inv * gv.x + bv.x;
        o.y = (v[i].y - mu) * inv * gv.y + bv.y;
        o.z = (v[i].z - mu) * inv * gv.z + bv.z;
        o.w = (v[i].w - mu) * inv * gv.w + bv.w;
        ((float4*)p)[i * 64 + l] = o;
    }
}

__global__ void __launch_bounds__(256)
concat_bias(const float* __restrict__ a, const float* __restrict__ b,
            const float* __restrict__ c, float* __restrict__ o)
{
    const int i = blockIdx.x * 256 + threadIdx.x;
    o[i] = (i < 512) ? a[i] : (i < 1024) ? b[i - 512] : c[i - 1024];
}

extern "C" void kernel_launch(void* const* d_in, const int* in_sizes, int n_in,
                              void* d_out, int out_size, void* d_ws, size_t ws_size,
                              hipStream_t stream)
{
    (void)in_sizes; (void)n_in; (void)out_size; (void)ws_size;

    const float* x = (const float*)d_in[0];
    const float* h = (const float*)d_in[1];
    const float* Wf[9]; const float* bia[9];
    for (int g = 0; g < 3; ++g)
        for (int j = 0; j < 3; ++j) {
            Wf[g * 3 + j]  = (const float*)d_in[2 + g * 6 + j * 2];
            bia[g * 3 + j] = (const float*)d_in[2 + g * 6 + j * 2 + 1];
        }
    const float* gamma = (const float*)d_in[20];
    const float* beta  = (const float*)d_in[21];
    float* out = (float*)d_out;

    // allow 128 KiB dynamic LDS (capture-safe host-side attribute)
    const int LDS_BYTES = 131072;
    hipFuncSetAttribute((const void*)gemm256<EPI_BF16>,   hipFuncAttributeMaxDynamicSharedMemorySize, LDS_BYTES);
    hipFuncSetAttribute((const void*)gemm256<EPI_SCORES>, hipFuncAttributeMaxDynamicSharedMemorySize, LDS_BYTES);
    hipFuncSetAttribute((const void*)gemm256<EPI_R>,      hipFuncAttributeMaxDynamicSharedMemorySize, LDS_BYTES);
    hipFuncSetAttribute((const void*)gemm256<EPI_Z>,      hipFuncAttributeMaxDynamicSharedMemorySize, LDS_BYTES);
    hipFuncSetAttribute((const void*)gemm256<EPI_N>,      hipFuncAttributeMaxDynamicSharedMemorySize, LDS_BYTES);

    char* ws = (char*)d_ws;
    size_t off = 0;
    auto alloc = [&](size_t bytes) -> void* {
        void* p = ws + off; off += (bytes + 255) & ~(size_t)255; return p;
    };
    unsigned short* xh  = (unsigned short*)alloc((size_t)32768 * 2048 * 2);
    unsigned short* WT  = (unsigned short*)alloc((size_t)12582912 * 2);
    unsigned short* QKV = (unsigned short*)alloc((size_t)32768 * 2048 * 2);
    unsigned short* Vt  = (unsigned short*)alloc((size_t)32768 * 1024 * 2);
    float*          Sc  = (float*)alloc((size_t)64 * 512 * 512 * 4);
    unsigned short* Pb  = (unsigned short*)alloc((size_t)64 * 512 * 512 * 2);
    unsigned short* upd = (unsigned short*)alloc((size_t)32768 * 1024 * 2);
    float*          bct = (float*)alloc((size_t)3 * 2048 * 4);

    size_t wtoff[9];
    {
        size_t o = 0;
        for (int g = 0; g < 3; ++g) {
            wtoff[g * 3 + 0] = o; o += (size_t)512 * 2048;
            wtoff[g * 3 + 1] = o; o += (size_t)512 * 2048;
            wtoff[g * 3 + 2] = o; o += (size_t)1024 * 2048;
        }
    }

    prep_xh<<<32768, 256, 0, stream>>>(x, h, xh);
    for (int i = 0; i < 9; ++i) {
        const int N = (i % 3 == 2) ? 1024 : 512;
        transpose_w<<<dim3(N / 32, 64, 1), 256, 0, stream>>>(Wf[i], WT + wtoff[i], N);
    }
    for (int g = 0; g < 3; ++g)
        concat_bias<<<8, 256, 0, stream>>>(bia[g * 3 + 0], bia[g * 3 + 1], bia[g * 3 + 2], bct + g * 2048);

    const float scscale = 0.044194173824159216f; // 1/sqrt(512)

    auto gate = [&](int g, int epi) {
        const unsigned short* wT = WT + wtoff[g * 3 + 0];
        // fused QKV projection: (32768 x 2048) @ (2048 x 2048)^T
        gemm256<EPI_BF16><<<dim3(8, 128, 1), 512, LDS_BYTES, stream>>>(
            xh, 0, 2048, wT, 0, 2048, bct + g * 2048, QKV, 0, 2048, 2048, 0.0f, nullptr, nullptr);
        transpose_v<<<dim3(32, 16, 64), 256, 0, stream>>>(QKV + 1024, Vt);
        // scores = Q @ K^T * scale (batched over 64)
        gemm256<EPI_SCORES><<<dim3(2, 2, 64), 512, LDS_BYTES, stream>>>(
            QKV, 1048576, 2048, QKV + 512, 1048576, 2048, nullptr,
            Sc, 262144, 512, 512, scscale, nullptr, nullptr);
        softmax512<<<8192, 256, 0, stream>>>(Sc, Pb);
        // PV (batched), fused gate epilogue
        if (epi == EPI_Z)
            gemm256<EPI_Z><<<dim3(4, 2, 64), 512, LDS_BYTES, stream>>>(
                Pb, 262144, 512, Vt, 524288, 512, nullptr, upd, 0, 1024, 512, 0.0f, nullptr, nullptr);
        else if (epi == EPI_R)
            gemm256<EPI_R><<<dim3(4, 2, 64), 512, LDS_BYTES, stream>>>(
                Pb, 262144, 512, Vt, 524288, 512, nullptr, xh, 0, 2048, 512, 0.0f, h, nullptr);
        else
            gemm256<EPI_N><<<dim3(4, 2, 64), 512, LDS_BYTES, stream>>>(
                Pb, 262144, 512, Vt, 524288, 512, nullptr, out, 0, 1024, 512, 0.0f, h, upd);
    };

    gate(1, EPI_Z);  // update = sigmoid(z-attn)            (reads original xh)
    gate(0, EPI_R);  // xh[:,1024:] = bf16(h * sigmoid(r))  (in-place -> xhr)
    gate(2, EPI_N);  // out = (1-u)*h + u*tanh(n-attn)
    layernorm1024<<<8192, 256, 0, stream>>>(out, gamma, beta);
}

// Round 3
// 1574.720 us; speedup vs baseline: 1.3056x; 1.0072x over previous
//
#include <hip/hip_runtime.h>
#include <math.h>

typedef __attribute__((ext_vector_type(8))) short short8;
typedef __attribute__((ext_vector_type(4))) float f32x4;

#define EPI_BF16   0
#define EPI_SCORES 1
#define EPI_R      2
#define EPI_Z      3
#define EPI_N      4

__device__ __forceinline__ unsigned short f2bf(float f) {
    unsigned int u = __float_as_uint(f);
    u += 0x7fffu + ((u >> 16) & 1u);
    return (unsigned short)(u >> 16);
}
__device__ __forceinline__ float bf2f(unsigned short s) {
    return __uint_as_float(((unsigned int)s) << 16);
}

struct alignas(8) us4 { unsigned short a, b, c, d; };

#define GLD_LDS16(gp, lp) \
    __builtin_amdgcn_global_load_lds((const __attribute__((address_space(1))) unsigned int*)(gp), \
                                     (__attribute__((address_space(3))) unsigned int*)(lp), 16, 0, 0)

__device__ __forceinline__ void BARF() {
    asm volatile("" ::: "memory");
    __builtin_amdgcn_s_barrier();
    asm volatile("" ::: "memory");
}
#define LGKM0 asm volatile("s_waitcnt lgkmcnt(0)" ::: "memory")

// ============================================================================
// 256x256 tile, BK=64, 512 threads (8 waves: 2M x 4N), 4-phase pipeline,
// XOR-swizzled LDS (T2), counted vmcnt (T4), setprio (T5), kk-outer MFMA
// ordering (dep distance 8), optional XCD-bijective block swizzle (T1) for
// the (8,128) QKV grid: xcd=bid&7 keeps all 8 col-blocks of a row-panel on
// one XCD's L2 -> A fetched ~once instead of ~4x.
// ============================================================================
template<int EPI, int SWZ>
__global__ void __launch_bounds__(512, 2)
gemm256(const unsigned short* __restrict__ A, long long sAb, int lda,
        const unsigned short* __restrict__ Bt, long long sBb, int ldb,
        const float* __restrict__ bias,
        void* __restrict__ C, long long sCb, int ldc,
        int K, float scale,
        const float* __restrict__ hptr,
        const unsigned short* __restrict__ updptr)
{
    extern __shared__ char smem[];   // 131072 B

    const int z = blockIdx.z;
    A  += (size_t)z * (size_t)sAb;
    Bt += (size_t)z * (size_t)sBb;

    int bx, by;
    if (SWZ) {
        const int bid = blockIdx.y * 8 + blockIdx.x;   // grid (8,128)
        const int xcd = bid & 7, i = bid >> 3;
        bx = i & 7;
        by = (xcd << 4) | (i >> 3);
    } else {
        bx = blockIdx.x; by = blockIdx.y;
    }
    const int m0 = by * 256;
    const int n0 = bx * 256;

    const int tid = threadIdx.x;
    const int w  = tid >> 6;      // wave 0..7
    const int l  = tid & 63;
    const int wr = w >> 2;        // 0..1 (M half: 128 rows)
    const int wc = w & 3;         // 0..3 (N quarter: 64 cols)
    const int lr = l & 15;
    const int lg = l >> 4;
    const int rs = (lr & 7) << 4; // read-side XOR swizzle

    const int srw = l >> 3;
    const int scb = ((l & 7) << 4) ^ (srw << 4);  // inverse-swizzled source col byte
    const int ldsw = w << 10;                      // wave's 1 KiB chunk

    const long long ldab = (long long)lda * 2;
    const long long ldbb = (long long)ldb * 2;

    f32x4 acc[2][4][4] = {};
    short8 a[4][2], b[4][2];

#define STAGE_A(kt, buf) { \
    const char* g_ = (const char*)A + (size_t)(m0 + w*8 + srw) * ldab + (size_t)(kt)*2 + scb; \
    char* d_ = smem + (buf)*65536 + ldsw; \
    _Pragma("unroll") \
    for (int j = 0; j < 4; ++j) \
        GLD_LDS16(g_ + (size_t)(j*64) * ldab, d_ + j*8192); }

#define STAGE_B(kt, buf) { \
    const char* g_ = (const char*)Bt + (size_t)(n0 + w*8 + srw) * ldbb + (size_t)(kt)*2 + scb; \
    char* d_ = smem + (buf)*65536 + 32768 + ldsw; \
    _Pragma("unroll") \
    for (int j = 0; j < 4; ++j) \
        GLD_LDS16(g_ + (size_t)(j*64) * ldbb, d_ + j*8192); }

#define LDA8(MH, buf) { \
    const char* Ab_ = smem + (buf)*65536; \
    _Pragma("unroll") \
    for (int mf = 0; mf < 4; ++mf) { \
        const int row_ = wr*128 + (MH)*64 + mf*16 + lr; \
        _Pragma("unroll") \
        for (int kk = 0; kk < 2; ++kk) \
            a[mf][kk] = *(const short8*)(Ab_ + row_*128 + ((kk*64 + lg*16) ^ rs)); } }

#define LDB4(BH, buf) { \
    const char* Bb_ = smem + (buf)*65536 + 32768; \
    _Pragma("unroll") \
    for (int nf = 0; nf < 2; ++nf) { \
        const int row_ = wc*64 + (BH)*32 + nf*16 + lr; \
        _Pragma("unroll") \
        for (int kk = 0; kk < 2; ++kk) \
            b[(BH)*2+nf][kk] = *(const short8*)(Bb_ + row_*128 + ((kk*64 + lg*16) ^ rs)); } }

// kk OUTER: dependent MFMAs on the same acc are 8 apart (~38 cy) -> no
// result-latency stall with only 2 waves/SIMD.
#define MMA16(MH, BH) { \
    __builtin_amdgcn_s_setprio(1); \
    _Pragma("unroll") \
    for (int kk = 0; kk < 2; ++kk) \
    _Pragma("unroll") \
    for (int mf = 0; mf < 4; ++mf) \
    _Pragma("unroll") \
    for (int nf = 0; nf < 2; ++nf) \
        acc[MH][mf][(BH)*2+nf] = __builtin_amdgcn_mfma_f32_16x16x32_bf16( \
            a[mf][kk], b[(BH)*2+nf][kk], acc[MH][mf][(BH)*2+nf], 0, 0, 0); \
    __builtin_amdgcn_s_setprio(0); }

    // prologue: tile 0 -> buf0, tile 1 -> buf1
    STAGE_A(0, 0); STAGE_B(0, 0);
    STAGE_A(64, 1); STAGE_B(64, 1);
    asm volatile("s_waitcnt vmcnt(8)" ::: "memory");   // tile 0 landed
    BARF();

    const int NT = K >> 6;
    for (int t = 0; t < NT; ++t) {
        const int p = t & 1;
        // phase 0: A-lo(8 reads) + B-lo(4); MFMA (mh0 x bh0)
        LDA8(0, p); LDB4(0, p);
        BARF(); LGKM0;
        MMA16(0, 0);
        BARF();
        // phase 1: B-hi(4); MFMA (mh0 x bh1)
        LDB4(1, p);
        BARF(); LGKM0;
        MMA16(0, 1);
        BARF();
        // phase 2: A-hi(8); MFMA (mh1 x bh1)  -> buf p fully consumed after this
        LDA8(1, p);
        BARF(); LGKM0;
        MMA16(1, 1);
        BARF();
        // phase 3: stage tile t+2 into buf p; counted vmcnt guarantees tile t+1
        if (t + 2 < NT) {
            STAGE_A((t + 2) * 64, p); STAGE_B((t + 2) * 64, p);
            asm volatile("s_waitcnt vmcnt(8)" ::: "memory");
        } else {
            asm volatile("s_waitcnt vmcnt(0)" ::: "memory");
        }
        BARF();
        MMA16(1, 0);                 // regs only (a=mh1, b=bh0)
        BARF();
    }

    // epilogue
    const int Mb = gridDim.y << 8;
    const size_t zc = (size_t)z * (size_t)sCb;
    #pragma unroll
    for (int mh = 0; mh < 2; ++mh) {
        #pragma unroll
        for (int mf = 0; mf < 4; ++mf) {
            #pragma unroll
            for (int nf = 0; nf < 4; ++nf) {
                const int col = n0 + wc * 64 + nf * 16 + lr;
                const float bval = (EPI == EPI_BF16) ? bias[col] : 0.0f;
                #pragma unroll
                for (int r = 0; r < 4; ++r) {
                    const int row = m0 + wr * 128 + mh * 64 + mf * 16 + lg * 4 + r;
                    float v = acc[mh][mf][nf][r] + bval;
                    if (EPI == EPI_BF16) {
                        ((unsigned short*)C)[zc + (size_t)row * ldc + col] = f2bf(v);
                    } else if (EPI == EPI_SCORES) {
                        ((float*)C)[zc + (size_t)row * ldc + col] = v * scale;
                    } else if (EPI == EPI_R) {
                        const size_t flat = (size_t)z * Mb + row;
                        const float hh = hptr[flat * 1024 + col];
                        const float sg = 1.0f / (1.0f + __expf(-v));
                        ((unsigned short*)C)[flat * 2048 + 1024 + col] = f2bf(hh * sg);
                    } else if (EPI == EPI_Z) {
                        const size_t flat = (size_t)z * Mb + row;
                        const float sg = 1.0f / (1.0f + __expf(-v));
                        ((unsigned short*)C)[flat * 1024 + col] = f2bf(sg);
                    } else { // EPI_N
                        const size_t flat = (size_t)z * Mb + row;
                        const float u  = bf2f(updptr[flat * 1024 + col]);
                        const float hh = hptr[flat * 1024 + col];
                        ((float*)C)[flat * 1024 + col] = (1.0f - u) * hh + u * tanhf(v);
                    }
                }
            }
        }
    }
#undef STAGE_A
#undef STAGE_B
#undef LDA8
#undef LDB4
#undef MMA16
}

// ============================================================================
// memory-bound helper kernels
// ============================================================================

__global__ void __launch_bounds__(256)
prep_xh(const float* __restrict__ x, const float* __restrict__ h, unsigned short* __restrict__ xh)
{
    const size_t t = (size_t)blockIdx.x * 256 + threadIdx.x;
    const size_t f = t * 4;
    const size_t row = f >> 10, col = f & 1023;
    const float4 vx = *(const float4*)(x + f);
    const float4 vh = *(const float4*)(h + f);
    us4 ox = { f2bf(vx.x), f2bf(vx.y), f2bf(vx.z), f2bf(vx.w) };
    us4 oh = { f2bf(vh.x), f2bf(vh.y), f2bf(vh.z), f2bf(vh.w) };
    *(us4*)(xh + row * 2048 + col)        = ox;
    *(us4*)(xh + row * 2048 + 1024 + col) = oh;
}

__global__ void __launch_bounds__(256)
transpose_w(const float* __restrict__ W, unsigned short* __restrict__ WT, int N)
{
    __shared__ float t[32][33];
    const int k0 = blockIdx.y * 32, n0 = blockIdx.x * 32;
    const int tx = threadIdx.x & 31, ty = threadIdx.x >> 5;
    #pragma unroll
    for (int i = 0; i < 4; ++i)
        t[ty + i * 8][tx] = W[(size_t)(k0 + ty + i * 8) * N + n0 + tx];
    __syncthreads();
    #pragma unroll
    for (int i = 0; i < 4; ++i)
        WT[(size_t)(n0 + ty + i * 8) * 2048 + k0 + tx] = f2bf(t[tx][ty + i * 8]);
}

__global__ void __launch_bounds__(256)
transpose_v(const unsigned short* __restrict__ V, unsigned short* __restrict__ Vt)
{
    __shared__ unsigned short t[32][34];
    const int z = blockIdx.z;
    const unsigned short* in = V + (size_t)z * 512 * 2048;
    unsigned short* outp = Vt + (size_t)z * 1024 * 512;
    const int c0 = blockIdx.x * 32, r0 = blockIdx.y * 32;
    const int tx = threadIdx.x & 31, ty = threadIdx.x >> 5;
    #pragma unroll
    for (int i = 0; i < 4; ++i)
        t[ty + i * 8][tx] = in[(size_t)(r0 + ty + i * 8) * 2048 + c0 + tx];
    __syncthreads();
    #pragma unroll
    for (int i = 0; i < 4; ++i)
        outp[(size_t)(c0 + ty + i * 8) * 512 + r0 + tx] = t[tx][ty + i * 8];
}

__global__ void __launch_bounds__(256)
softmax512(const float* __restrict__ S, unsigned short* __restrict__ P)
{
    const int row = blockIdx.x * 4 + (threadIdx.x >> 6);
    const int l = threadIdx.x & 63;
    const float* s = S + (size_t)row * 512;
    const float4 v0 = ((const float4*)s)[l];
    const float4 v1 = ((const float4*)s)[64 + l];
    float m = fmaxf(fmaxf(fmaxf(v0.x, v0.y), fmaxf(v0.z, v0.w)),
                    fmaxf(fmaxf(v1.x, v1.y), fmaxf(v1.z, v1.w)));
    #pragma unroll
    for (int d = 32; d; d >>= 1) m = fmaxf(m, __shfl_xor(m, d));
    float e0 = __expf(v0.x - m), e1 = __expf(v0.y - m), e2 = __expf(v0.z - m), e3 = __expf(v0.w - m);
    float e4 = __expf(v1.x - m), e5 = __expf(v1.y - m), e6 = __expf(v1.z - m), e7 = __expf(v1.w - m);
    float sum = e0 + e1 + e2 + e3 + e4 + e5 + e6 + e7;
    #pragma unroll
    for (int d = 32; d; d >>= 1) sum += __shfl_xor(sum, d);
    const float inv = 1.0f / sum;
    unsigned short* p = P + (size_t)row * 512;
    us4 aa = { f2bf(e0 * inv), f2bf(e1 * inv), f2bf(e2 * inv), f2bf(e3 * inv) };
    us4 bb = { f2bf(e4 * inv), f2bf(e5 * inv), f2bf(e6 * inv), f2bf(e7 * inv) };
    ((us4*)p)[l] = aa;
    ((us4*)p)[64 + l] = bb;
}

__global__ void __launch_bounds__(256)
layernorm1024(float* __restrict__ Y, const float* __restrict__ gamma, const float* __restrict__ beta)
{
    const int row = blockIdx.x * 4 + (threadIdx.x >> 6);
    const int l = threadIdx.x & 63;
    float* p = Y + (size_t)row * 1024;
    float4 v[4];
    float s = 0.0f, s2 = 0.0f;
    #pragma unroll
    for (int i = 0; i < 4; ++i) {
        v[i] = ((const float4*)p)[i * 64 + l];
        s  += v[i].x + v[i].y + v[i].z + v[i].w;
        s2 += v[i].x * v[i].x + v[i].y * v[i].y + v[i].z * v[i].z + v[i].w * v[i].w;
    }
    #pragma unroll
    for (int d = 32; d; d >>= 1) { s += __shfl_xor(s, d); s2 += __shfl_xor(s2, d); }
    const float mu = s * (1.0f / 1024.0f);
    const float var = s2 * (1.0f / 1024.0f) - mu * mu;
    const float inv = rsqrtf(var + 1e-5f);
    #pragma unroll
    for (int i = 0; i < 4; ++i) {
        const float4 gv = ((const float4*)gamma)[i * 64 + l];
        const float4 bv = ((const float4*)beta)[i * 64 + l];
        float4 o;
        o.x = (v[i].x - mu) * inv * gv.x + bv.x;
        o.y = (v[i].y - mu) * inv * gv.y + bv.y;
        o.z = (v[i].z - mu) * inv * gv.z + bv.z;
        o.w = (v[i].w - mu) * inv * gv.w + bv.w;
        ((float4*)p)[i * 64 + l] = o;
    }
}

__global__ void __launch_bounds__(256)
concat_bias(const float* __restrict__ a, const float* __restrict__ b,
            const float* __restrict__ c, float* __restrict__ o)
{
    const int i = blockIdx.x * 256 + threadIdx.x;
    o[i] = (i < 512) ? a[i] : (i < 1024) ? b[i - 512] : c[i - 1024];
}

extern "C" void kernel_launch(void* const* d_in, const int* in_sizes, int n_in,
                              void* d_out, int out_size, void* d_ws, size_t ws_size,
                              hipStream_t stream)
{
    (void)in_sizes; (void)n_in; (void)out_size; (void)ws_size;

    const float* x = (const float*)d_in[0];
    const float* h = (const float*)d_in[1];
    const float* Wf[9]; const float* bia[9];
    for (int g = 0; g < 3; ++g)
        for (int j = 0; j < 3; ++j) {
            Wf[g * 3 + j]  = (const float*)d_in[2 + g * 6 + j * 2];
            bia[g * 3 + j] = (const float*)d_in[2 + g * 6 + j * 2 + 1];
        }
    const float* gamma = (const float*)d_in[20];
    const float* beta  = (const float*)d_in[21];
    float* out = (float*)d_out;

    const int LDS_BYTES = 131072;
    hipFuncSetAttribute((const void*)gemm256<EPI_BF16, 1>,   hipFuncAttributeMaxDynamicSharedMemorySize, LDS_BYTES);
    hipFuncSetAttribute((const void*)gemm256<EPI_SCORES, 0>, hipFuncAttributeMaxDynamicSharedMemorySize, LDS_BYTES);
    hipFuncSetAttribute((const void*)gemm256<EPI_R, 0>,      hipFuncAttributeMaxDynamicSharedMemorySize, LDS_BYTES);
    hipFuncSetAttribute((const void*)gemm256<EPI_Z, 0>,      hipFuncAttributeMaxDynamicSharedMemorySize, LDS_BYTES);
    hipFuncSetAttribute((const void*)gemm256<EPI_N, 0>,      hipFuncAttributeMaxDynamicSharedMemorySize, LDS_BYTES);

    char* ws = (char*)d_ws;
    size_t off = 0;
    auto alloc = [&](size_t bytes) -> void* {
        void* p = ws + off; off += (bytes + 255) & ~(size_t)255; return p;
    };
    unsigned short* xh  = (unsigned short*)alloc((size_t)32768 * 2048 * 2);
    unsigned short* WT  = (unsigned short*)alloc((size_t)12582912 * 2);
    unsigned short* QKV = (unsigned short*)alloc((size_t)32768 * 2048 * 2);
    unsigned short* Vt  = (unsigned short*)alloc((size_t)32768 * 1024 * 2);
    float*          Sc  = (float*)alloc((size_t)64 * 512 * 512 * 4);
    unsigned short* Pb  = (unsigned short*)alloc((size_t)64 * 512 * 512 * 2);
    unsigned short* upd = (unsigned short*)alloc((size_t)32768 * 1024 * 2);
    float*          bct = (float*)alloc((size_t)3 * 2048 * 4);

    size_t wtoff[9];
    {
        size_t o = 0;
        for (int g = 0; g < 3; ++g) {
            wtoff[g * 3 + 0] = o; o += (size_t)512 * 2048;
            wtoff[g * 3 + 1] = o; o += (size_t)512 * 2048;
            wtoff[g * 3 + 2] = o; o += (size_t)1024 * 2048;
        }
    }

    prep_xh<<<32768, 256, 0, stream>>>(x, h, xh);
    for (int i = 0; i < 9; ++i) {
        const int N = (i % 3 == 2) ? 1024 : 512;
        transpose_w<<<dim3(N / 32, 64, 1), 256, 0, stream>>>(Wf[i], WT + wtoff[i], N);
    }
    for (int g = 0; g < 3; ++g)
        concat_bias<<<8, 256, 0, stream>>>(bia[g * 3 + 0], bia[g * 3 + 1], bia[g * 3 + 2], bct + g * 2048);

    const float scscale = 0.044194173824159216f; // 1/sqrt(512)

    auto gate = [&](int g, int epi) {
        const unsigned short* wT = WT + wtoff[g * 3 + 0];
        // fused QKV projection: (32768 x 2048) @ (2048 x 2048)^T, XCD-swizzled
        gemm256<EPI_BF16, 1><<<dim3(8, 128, 1), 512, LDS_BYTES, stream>>>(
            xh, 0, 2048, wT, 0, 2048, bct + g * 2048, QKV, 0, 2048, 2048, 0.0f, nullptr, nullptr);
        transpose_v<<<dim3(32, 16, 64), 256, 0, stream>>>(QKV + 1024, Vt);
        // scores = Q @ K^T * scale (batched over 64)
        gemm256<EPI_SCORES, 0><<<dim3(2, 2, 64), 512, LDS_BYTES, stream>>>(
            QKV, 1048576, 2048, QKV + 512, 1048576, 2048, nullptr,
            Sc, 262144, 512, 512, scscale, nullptr, nullptr);
        softmax512<<<8192, 256, 0, stream>>>(Sc, Pb);
        // PV (batched), fused gate epilogue
        if (epi == EPI_Z)
            gemm256<EPI_Z, 0><<<dim3(4, 2, 64), 512, LDS_BYTES, stream>>>(
                Pb, 262144, 512, Vt, 524288, 512, nullptr, upd, 0, 1024, 512, 0.0f, nullptr, nullptr);
        else if (epi == EPI_R)
            gemm256<EPI_R, 0><<<dim3(4, 2, 64), 512, LDS_BYTES, stream>>>(
                Pb, 262144, 512, Vt, 524288, 512, nullptr, xh, 0, 2048, 512, 0.0f, h, nullptr);
        else
            gemm256<EPI_N, 0><<<dim3(4, 2, 64), 512, LDS_BYTES, stream>>>(
                Pb, 262144, 512, Vt, 524288, 512, nullptr, out, 0, 1024, 512, 0.0f, h, upd);
    };

    gate(1, EPI_Z);  // update = sigmoid(z-attn)            (reads original xh)
    gate(0, EPI_R);  // xh[:,1024:] = bf16(h * sigmoid(r))  (in-place -> xhr)
    gate(2, EPI_N);  // out = (1-u)*h + u*tanh(n-attn)
    layernorm1024<<<8192, 256, 0, stream>>>(out, gamma, beta);
}